// Round 1
// baseline (249.368 us; speedup 1.0000x reference)
//
#include <hip/hip_runtime.h>
#include <math.h>

// PCEN: per-(b,k) IIR smoother over T + pointwise pow compression.
// x: [B=32, C=1, K=128, T=8000] fp32. One block per sequence (4096 blocks),
// 256 threads, 32 contiguous elements per thread (250 active threads).
// Linear recurrence parallelized as an affine-map scan.

constexpr int   T_LEN = 8000;
constexpr int   CHUNK = 32;
constexpr int   NTH   = 256;
constexpr int   KDIM  = 128;
constexpr float EPS_F = 1e-6f;

__global__ __launch_bounds__(NTH) void pcen_kernel(
    const float* __restrict__ x,
    const float* __restrict__ log_s,
    const float* __restrict__ log_alpha,
    const float* __restrict__ log_delta,
    const float* __restrict__ log_r,
    float* __restrict__ out)
{
    const int seq  = blockIdx.x;          // seq = b*K + k  (C == 1)
    const int k    = seq % KDIM;
    const int tid  = threadIdx.x;
    const int lane = tid & 63;
    const int wave = tid >> 6;

    // Per-k parameters (uniform across the block) — precise once-per-thread math.
    const float s       = 1.0f / (1.0f + expf(-log_s[k]));   // sigmoid
    const float a       = 1.0f - s;
    const float alpha   = expf(log_alpha[k]);
    const float delta   = expf(log_delta[k]);
    const float r       = expf(log_r[k]);
    const float delta_r = powf(delta, r);

    const float* xp = x   + (size_t)seq * T_LEN + tid * CHUNK;
    float*       op = out + (size_t)seq * T_LEN + tid * CHUNK;
    const bool active = (tid * CHUNK) < T_LEN;   // tid < 250

    // ---- load 32 contiguous floats (one 128B line per lane) ----
    float xv[CHUNK];
    if (active) {
        #pragma unroll
        for (int j = 0; j < CHUNK / 4; ++j) {
            float4 v = ((const float4*)xp)[j];
            xv[4*j+0] = v.x; xv[4*j+1] = v.y; xv[4*j+2] = v.z; xv[4*j+3] = v.w;
        }
    }

    // ---- per-thread affine carry (A, B): f_out = A * f_in + B ----
    float A = 1.0f, B = 0.0f;     // identity for inactive tail threads
    if (active) {
        float f;
        if (tid == 0) {
            // f[0] = x[0] special case -> constant map (A = 0)
            f = xv[0];
            #pragma unroll
            for (int j = 1; j < CHUNK; ++j) f = fmaf(a, f, s * xv[j]);
            A = 0.0f;
        } else {
            f = 0.0f;
            #pragma unroll
            for (int j = 0; j < CHUNK; ++j) f = fmaf(a, f, s * xv[j]);
            const float a2 = a * a, a4 = a2 * a2, a8 = a4 * a4, a16 = a8 * a8;
            A = a16 * a16;        // a^32
        }
        B = f;
    }

    // ---- intra-wave inclusive scan (64 lanes), compose later∘earlier ----
    #pragma unroll
    for (int off = 1; off < 64; off <<= 1) {
        const float pA = __shfl_up(A, off, 64);
        const float pB = __shfl_up(B, off, 64);
        if (lane >= off) {
            B = fmaf(A, pB, B);
            A = A * pA;
        }
    }

    // ---- cross-wave combine via LDS (4 waves) ----
    __shared__ float wAs[NTH / 64], wBs[NTH / 64];
    if (lane == 63) { wAs[wave] = A; wBs[wave] = B; }
    __syncthreads();

    float pA = 1.0f, pB = 0.0f;           // prefix of waves before mine
    for (int w = 0; w < wave; ++w) {
        pB = fmaf(wAs[w], pB, wBs[w]);
        pA = wAs[w] * pA;
    }

    // exclusive (incoming) value for this thread:
    float eA = __shfl_up(A, 1, 64);
    float eB = __shfl_up(B, 1, 64);
    if (lane == 0) { eA = 1.0f; eB = 0.0f; }
    // Thread 0's constant map (A=0) kills any dependence on a fictitious f_init,
    // so incoming f = eA*pB + eB for every tid > 0 (tid 0 never uses it).
    const float fin = fmaf(eA, pB, eB);

    // ---- replay recurrence with true incoming f, apply PCEN pointwise ----
    if (active) {
        float f = fin;
        #pragma unroll
        for (int j = 0; j < CHUNK; ++j) {
            if (tid == 0 && j == 0) f = xv[0];
            else                    f = fmaf(a, f, s * xv[j]);
            const float lg  = __log2f(EPS_F + f);
            const float inv = exp2f(-alpha * lg);          // (eps+f)^(-alpha)
            const float u   = fmaf(xv[j], inv, delta);
            xv[j] = exp2f(r * __log2f(u)) - delta_r;       // (u)^r - delta^r
        }
        #pragma unroll
        for (int j = 0; j < CHUNK / 4; ++j) {
            ((float4*)op)[j] = make_float4(xv[4*j+0], xv[4*j+1], xv[4*j+2], xv[4*j+3]);
        }
    }
}

extern "C" void kernel_launch(void* const* d_in, const int* in_sizes, int n_in,
                              void* d_out, int out_size, void* d_ws, size_t ws_size,
                              hipStream_t stream) {
    const float* x         = (const float*)d_in[0];
    const float* log_s     = (const float*)d_in[1];
    const float* log_alpha = (const float*)d_in[2];
    const float* log_delta = (const float*)d_in[3];
    const float* log_r     = (const float*)d_in[4];
    float* out = (float*)d_out;

    const int nseq = in_sizes[0] / T_LEN;   // 32*1*128 = 4096 sequences
    pcen_kernel<<<nseq, NTH, 0, stream>>>(x, log_s, log_alpha, log_delta, log_r, out);
}

// Round 2
// 242.648 us; speedup vs baseline: 1.0277x; 1.0277x over previous
//
#include <hip/hip_runtime.h>
#include <math.h>

// PCEN: per-(b,k) IIR smoother over T + pointwise pow compression.
// x: [B=32, C=1, K=128, T=8000] fp32. One block per sequence (4096 blocks).
// R2: LDS-staged version. All global traffic is lane-coalesced float4;
// per-element work reads/writes LDS with +1-pad (conflict-free).
// 512 threads, CHUNK=16 -> 500 active compute threads, 8-wave affine scan.

constexpr int   T_LEN  = 8000;
constexpr int   CHUNK  = 16;
constexpr int   NTH    = 512;
constexpr int   NWAVE  = NTH / 64;
constexpr int   KDIM   = 128;
constexpr int   NVEC4  = T_LEN / 4;            // 2000 float4 per sequence
constexpr int   PSTRIDE = CHUNK + 1;           // 17 floats per chunk (padded)
constexpr int   LDS_FLOATS = (T_LEN / CHUNK) * PSTRIDE;  // 500*17 = 8500
constexpr float EPS_F  = 1e-6f;

__global__ __launch_bounds__(NTH) void pcen_kernel(
    const float* __restrict__ x,
    const float* __restrict__ log_s,
    const float* __restrict__ log_alpha,
    const float* __restrict__ log_delta,
    const float* __restrict__ log_r,
    float* __restrict__ out)
{
    __shared__ float lds[LDS_FLOATS];
    __shared__ float wAs[NWAVE], wBs[NWAVE];

    const int seq  = blockIdx.x;          // seq = b*K + k  (C == 1)
    const int k    = seq % KDIM;
    const int tid  = threadIdx.x;
    const int lane = tid & 63;
    const int wave = tid >> 6;

    // Per-k parameters (uniform across the block).
    const float s       = 1.0f / (1.0f + expf(-log_s[k]));   // sigmoid
    const float a       = 1.0f - s;
    const float alpha   = expf(log_alpha[k]);
    const float delta   = expf(log_delta[k]);
    const float r       = expf(log_r[k]);
    const float delta_r = powf(delta, r);

    const float* xseq = x   + (size_t)seq * T_LEN;
    float*       oseq = out + (size_t)seq * T_LEN;

    // ---- stage in: coalesced float4 global loads -> padded LDS ----
    #pragma unroll
    for (int i = tid; i < NVEC4; i += NTH) {
        float4 v = ((const float4*)xseq)[i];
        const int e    = 4 * i;                    // element index
        const int slot = (e >> 4) * PSTRIDE + (e & 15);
        lds[slot + 0] = v.x;
        lds[slot + 1] = v.y;
        lds[slot + 2] = v.z;
        lds[slot + 3] = v.w;
    }
    __syncthreads();

    const bool active = tid < (T_LEN / CHUNK);     // tid < 500
    const int  base   = tid * PSTRIDE;

    // ---- per-thread affine carry (A, B): f_out = A * f_in + B ----
    float A = 1.0f, B = 0.0f;                      // identity for inactive tail
    if (active) {
        float f;
        if (tid == 0) {
            f = lds[base];                         // f[0] = x[0]
            #pragma unroll
            for (int j = 1; j < CHUNK; ++j) f = fmaf(a, f, s * lds[base + j]);
            A = 0.0f;                              // constant map
        } else {
            f = 0.0f;
            #pragma unroll
            for (int j = 0; j < CHUNK; ++j) f = fmaf(a, f, s * lds[base + j]);
            const float a2 = a * a, a4 = a2 * a2, a8 = a4 * a4;
            A = a8 * a8;                           // a^16
        }
        B = f;
    }

    // ---- intra-wave inclusive scan (64 lanes), compose current∘previous ----
    #pragma unroll
    for (int off = 1; off < 64; off <<= 1) {
        const float pA = __shfl_up(A, off, 64);
        const float pB = __shfl_up(B, off, 64);
        if (lane >= off) {
            B = fmaf(A, pB, B);
            A = A * pA;
        }
    }

    // ---- cross-wave combine via LDS (8 waves) ----
    if (lane == 63) { wAs[wave] = A; wBs[wave] = B; }
    __syncthreads();

    float pB = 0.0f;                               // prefix of waves before mine
    for (int w = 0; w < wave; ++w) {
        pB = fmaf(wAs[w], pB, wBs[w]);
    }

    // exclusive (incoming) map for this thread within the wave:
    float eA = __shfl_up(A, 1, 64);
    float eB = __shfl_up(B, 1, 64);
    if (lane == 0) { eA = 1.0f; eB = 0.0f; }
    // Thread 0's constant map (A=0) kills dependence on any fictitious f_init,
    // so incoming f = eA*pB + eB (tid 0 never uses it).
    const float fin = fmaf(eA, pB, eB);

    // ---- replay with true incoming f; PCEN pointwise; write back to LDS ----
    if (active) {
        float f = fin;
        #pragma unroll
        for (int j = 0; j < CHUNK; ++j) {
            const float xj = lds[base + j];
            if (tid == 0 && j == 0) f = xj;
            else                    f = fmaf(a, f, s * xj);
            const float lg  = __log2f(EPS_F + f);
            const float inv = exp2f(-alpha * lg);          // (eps+f)^(-alpha)
            const float u   = fmaf(xj, inv, delta);
            lds[base + j] = exp2f(r * __log2f(u)) - delta_r;  // u^r - delta^r
        }
    }
    __syncthreads();

    // ---- stage out: padded LDS -> coalesced float4 global stores ----
    #pragma unroll
    for (int i = tid; i < NVEC4; i += NTH) {
        const int e    = 4 * i;
        const int slot = (e >> 4) * PSTRIDE + (e & 15);
        float4 v = make_float4(lds[slot + 0], lds[slot + 1],
                               lds[slot + 2], lds[slot + 3]);
        ((float4*)oseq)[i] = v;
    }
}

extern "C" void kernel_launch(void* const* d_in, const int* in_sizes, int n_in,
                              void* d_out, int out_size, void* d_ws, size_t ws_size,
                              hipStream_t stream) {
    const float* x         = (const float*)d_in[0];
    const float* log_s     = (const float*)d_in[1];
    const float* log_alpha = (const float*)d_in[2];
    const float* log_delta = (const float*)d_in[3];
    const float* log_r     = (const float*)d_in[4];
    float* out = (float*)d_out;

    const int nseq = in_sizes[0] / T_LEN;   // 32*1*128 = 4096 sequences
    pcen_kernel<<<nseq, NTH, 0, stream>>>(x, log_s, log_alpha, log_delta, log_r, out);
}

// Round 3
// 237.254 us; speedup vs baseline: 1.0511x; 1.0227x over previous
//
#include <hip/hip_runtime.h>
#include <math.h>

// PCEN: per-(b,k) IIR smoother over T + pointwise pow compression.
// x: [B=32, C=1, K=128, T=8000] fp32. One block per sequence (4096 blocks).
// R3: zero-LDS data path. 1024 threads, each owns 8 contiguous elements
// (two adjacent float4s -> fully register-resident, contiguous global access).
// Affine-map scan: 64-lane shfl scan + wave-0 scan of 16 wave carries.
// No replay: local zero-init prefixes q_j kept in regs; f_j = a^(j+1)*fin + q_j.

constexpr int   T_LEN = 8000;
constexpr int   CHUNK = 8;
constexpr int   NTH   = 1024;
constexpr int   NWAVE = NTH / 64;            // 16
constexpr int   NACT  = T_LEN / CHUNK;       // 1000 active threads
constexpr int   KDIM  = 128;
constexpr float EPS_F = 1e-6f;

__global__ __launch_bounds__(NTH, 8) void pcen_kernel(
    const float* __restrict__ x,
    const float* __restrict__ log_s,
    const float* __restrict__ log_alpha,
    const float* __restrict__ log_delta,
    const float* __restrict__ log_r,
    float* __restrict__ out)
{
    __shared__ float wAs[NWAVE], wBs[NWAVE];

    const int seq  = blockIdx.x;              // seq = b*K + k  (C == 1)
    const int k    = seq % KDIM;
    const int tid  = threadIdx.x;
    const int lane = tid & 63;
    const int wave = tid >> 6;

    // Per-k parameters (uniform across the block).
    const float s       = 1.0f / (1.0f + expf(-log_s[k]));   // sigmoid
    const float a       = 1.0f - s;
    const float alpha   = expf(log_alpha[k]);
    const float delta   = expf(log_delta[k]);
    const float r       = expf(log_r[k]);
    const float delta_r = exp2f(r * __log2f(delta));         // delta^r

    const float* xp = x   + (size_t)seq * T_LEN + tid * CHUNK;
    float*       op = out + (size_t)seq * T_LEN + tid * CHUNK;
    const bool active = tid < NACT;

    // ---- load 8 contiguous floats (two adjacent float4s), register-resident ----
    float xv[CHUNK];
    if (active) {
        float4 v0 = ((const float4*)xp)[0];
        float4 v1 = ((const float4*)xp)[1];
        xv[0] = v0.x; xv[1] = v0.y; xv[2] = v0.z; xv[3] = v0.w;
        xv[4] = v1.x; xv[5] = v1.y; xv[6] = v1.z; xv[7] = v1.w;
    }

    // ---- carry pass: local prefixes q_j with f_in = 0 (kept in regs) ----
    // Thread 0: f[0] = x[0] special case -> constant map (A = 0).
    float q[CHUNK];
    float A = 1.0f, B = 0.0f;                 // identity for inactive tail
    if (active) {
        float f;
        if (tid == 0) {
            f = xv[0]; q[0] = f;
            #pragma unroll
            for (int j = 1; j < CHUNK; ++j) { f = fmaf(a, f, s * xv[j]); q[j] = f; }
            A = 0.0f;
        } else {
            f = 0.0f;
            #pragma unroll
            for (int j = 0; j < CHUNK; ++j) { f = fmaf(a, f, s * xv[j]); q[j] = f; }
            const float a2 = a * a, a4 = a2 * a2;
            A = a4 * a4;                      // a^8
        }
        B = f;
    }

    // ---- intra-wave inclusive scan (64 lanes), compose current∘previous ----
    #pragma unroll
    for (int off = 1; off < 64; off <<= 1) {
        const float pA = __shfl_up(A, off, 64);
        const float pB = __shfl_up(B, off, 64);
        if (lane >= off) {
            B = fmaf(A, pB, B);
            A = A * pA;
        }
    }

    // ---- cross-wave: wave 0 scans the 16 wave carries, writes EXCLUSIVE prefixes ----
    if (lane == 63) { wAs[wave] = A; wBs[wave] = B; }
    __syncthreads();
    if (wave == 0) {
        float cA = (lane < NWAVE) ? wAs[lane] : 1.0f;
        float cB = (lane < NWAVE) ? wBs[lane] : 0.0f;
        #pragma unroll
        for (int off = 1; off < NWAVE; off <<= 1) {
            const float pA = __shfl_up(cA, off, 64);
            const float pB = __shfl_up(cB, off, 64);
            if (lane >= off) {
                cB = fmaf(cA, pB, cB);
                cA = cA * pA;
            }
        }
        if (lane < NWAVE - 1) { wAs[lane + 1] = cA; wBs[lane + 1] = cB; }
        if (lane == 0)        { wAs[0] = 1.0f;      wBs[0] = 0.0f;      }
    }
    __syncthreads();

    // incoming value for this thread: within-wave exclusive map applied to
    // the wave-prefix B. (Thread 0's A=0 map kills any f_init dependence, so
    // every wave-prefix for wave>=1 has A=0 and the entering value is just pB;
    // wave 0 threads >0 likewise compose through thread 0's A=0.)
    float eA = __shfl_up(A, 1, 64);
    float eB = __shfl_up(B, 1, 64);
    if (lane == 0) { eA = 1.0f; eB = 0.0f; }
    float fin = fmaf(eA, wBs[wave], eB);
    if (tid == 0) fin = 0.0f;                 // thread 0 uses q_j directly

    // ---- apply: f_j = a^(j+1)*fin + q_j ; PCEN pointwise; store ----
    if (active) {
        float pw = a;
        #pragma unroll
        for (int j = 0; j < CHUNK; ++j) {
            const float f   = fmaf(pw, fin, q[j]);
            pw *= a;
            const float lg  = __log2f(EPS_F + f);
            const float inv = exp2f(-alpha * lg);            // (eps+f)^(-alpha)
            const float u   = fmaf(xv[j], inv, delta);
            xv[j] = exp2f(r * __log2f(u)) - delta_r;         // u^r - delta^r
        }
        ((float4*)op)[0] = make_float4(xv[0], xv[1], xv[2], xv[3]);
        ((float4*)op)[1] = make_float4(xv[4], xv[5], xv[6], xv[7]);
    }
}

extern "C" void kernel_launch(void* const* d_in, const int* in_sizes, int n_in,
                              void* d_out, int out_size, void* d_ws, size_t ws_size,
                              hipStream_t stream) {
    const float* x         = (const float*)d_in[0];
    const float* log_s     = (const float*)d_in[1];
    const float* log_alpha = (const float*)d_in[2];
    const float* log_delta = (const float*)d_in[3];
    const float* log_r     = (const float*)d_in[4];
    float* out = (float*)d_out;

    const int nseq = in_sizes[0] / T_LEN;   // 32*1*128 = 4096 sequences
    pcen_kernel<<<nseq, NTH, 0, stream>>>(x, log_s, log_alpha, log_delta, log_r, out);
}